// Round 2
// baseline (1194.170 us; speedup 1.0000x reference)
//
#include <hip/hip_runtime.h>

// VectorQuantizer: latents (16,128,64,64) f32, codebook (1024,128) f32.
// out[b,d,h,w] = codebook[argmin_k ((x2 - 2*dot(x,e_k)) + e2_k)][d]
// Numerics replicate np: serial fp32 fma chain over d (ascending), then
// t3 = (x2 - 2*dot) + e2  (two roundings), argmin with first-index ties.
//
// Structure: block = 256 threads = 4 waves, owns 64 pixels.
//  - x-tile staged in LDS, chunk-major [32][64] float4 (std b128 pattern).
//  - lane = pixel; each wave scans a 256-code quarter of K (wave id forced
//    into an SGPR so cb addresses are provably uniform -> s_load, not VMEM).
//  - 16 codes in flight: 1 ds_read_b128 amortized over 64 FMAs.
//  - cross-wave argmin merge in LDS (wave order = k order, strict < keeps
//    first-index tie-break), then codebook-row writeback split over waves.

#define VQ_D    128
#define VQ_K    1024
#define VQ_HW   4096
#define VQ_NPIX 65536
#define WAVES   4
#define KPW     (VQ_K / WAVES)   // 256 codes per wave
#define CIF     16               // codes in flight

__global__ __launch_bounds__(128, 2)
void vq_e2_kernel(const float* __restrict__ cb, float* __restrict__ e2) {
    int k = blockIdx.x * blockDim.x + threadIdx.x;
    if (k < VQ_K) {
        float s = 0.f;
        #pragma unroll
        for (int d = 0; d < VQ_D; ++d) {
            float v = cb[k * VQ_D + d];
            s = fmaf(v, v, s);
        }
        e2[k] = s;
    }
}

__global__ __launch_bounds__(256, 4)
void vq_main_kernel(const float* __restrict__ latents,
                    const float4* __restrict__ cb4,
                    const float* __restrict__ e2,
                    float* __restrict__ out) {
    __shared__ float4 xlds[32 * 64];          // 32 KB x-tile
    __shared__ float  mval[WAVES][64];
    __shared__ int    midx[WAVES][64];

    const int tid  = threadIdx.x;
    const int lane = tid & 63;
    // Force wave id into an SGPR so everything derived from it (cb indices)
    // is provably wave-uniform -> scalar loads for the codebook.
    const int wave = __builtin_amdgcn_readfirstlane(tid >> 6);
    const int blk  = blockIdx.x;
    const int b    = blk >> 6;               // 64 blocks per image
    const int hw0  = (blk & 63) << 6;

    const float* xg = latents + (size_t)b * VQ_D * VQ_HW + hw0;

    // Stage x-tile: thread covers pix=lane, chunks c in [wave*8, wave*8+8).
    // Global reads coalesced across lanes (consecutive hw); LDS write is the
    // standard contiguous-lane b128 pattern.
    #pragma unroll
    for (int cc = 0; cc < 8; ++cc) {
        const int c = wave * 8 + cc;
        float4 v;
        v.x = xg[(size_t)(4 * c + 0) * VQ_HW + lane];
        v.y = xg[(size_t)(4 * c + 1) * VQ_HW + lane];
        v.z = xg[(size_t)(4 * c + 2) * VQ_HW + lane];
        v.w = xg[(size_t)(4 * c + 3) * VQ_HW + lane];
        xlds[c * 64 + lane] = v;
    }
    __syncthreads();

    // x2: ascending-d fma chain (any fp32 order is argmin-safe, keep simple).
    float x2 = 0.f;
    #pragma unroll
    for (int c = 0; c < 32; ++c) {
        float4 v = xlds[c * 64 + lane];
        x2 = fmaf(v.x, v.x, x2);
        x2 = fmaf(v.y, v.y, x2);
        x2 = fmaf(v.z, v.z, x2);
        x2 = fmaf(v.w, v.w, x2);
    }

    float best = 1e30f;
    int   bi   = 0;
    const int kbeg = wave * KPW;

    #pragma unroll 1
    for (int kt = 0; kt < KPW; kt += CIF) {
        const int k0 = kbeg + kt;            // wave-uniform (SGPR)
        float dot[CIF];
        #pragma unroll
        for (int j = 0; j < CIF; ++j) dot[j] = 0.f;

        #pragma unroll
        for (int c = 0; c < 32; ++c) {
            const float4 xv = xlds[c * 64 + lane];   // 1 ds_read_b128
            #pragma unroll
            for (int j = 0; j < CIF; ++j) {
                const float4 ev = cb4[(size_t)(k0 + j) * 32 + c]; // s_load
                dot[j] = fmaf(xv.x, ev.x, dot[j]);
                dot[j] = fmaf(xv.y, ev.y, dot[j]);
                dot[j] = fmaf(xv.z, ev.z, dot[j]);
                dot[j] = fmaf(xv.w, ev.w, dot[j]);
            }
        }

        #pragma unroll
        for (int j = 0; j < CIF; ++j) {
            // np rounding: t2 = fl(x2 - 2*dot) (2*dot exact), t3 = fl(t2+e2).
            const float t3 = (x2 - 2.0f * dot[j]) + e2[k0 + j];
            if (t3 < best) { best = t3; bi = k0 + j; }
        }
    }

    // Cross-wave merge. Wave order == k-range order, so strict < preserves
    // the first-index tie-break.
    __syncthreads();
    mval[wave][lane] = best;
    midx[wave][lane] = bi;
    __syncthreads();

    float fbest = mval[0][lane];
    int   fbi   = midx[0][lane];
    #pragma unroll
    for (int w = 1; w < WAVES; ++w) {
        const float v = mval[w][lane];
        const int   i = midx[w][lane];
        if (v < fbest) { fbest = v; fbi = i; }
    }

    // Writeback: thread covers pix=lane, d-range [wave*32, wave*32+32).
    // Store coalesced across lanes; cb read is a per-lane gather (L1/L2).
    const float* cbf = (const float*)cb4;
    const float* crow = cbf + (size_t)fbi * VQ_D;
    float* og = out + (size_t)b * VQ_D * VQ_HW + hw0;
    #pragma unroll
    for (int dd = 0; dd < 32; ++dd) {
        const int d = wave * 32 + dd;
        og[(size_t)d * VQ_HW + lane] = crow[d];
    }
}

extern "C" void kernel_launch(void* const* d_in, const int* in_sizes, int n_in,
                              void* d_out, int out_size, void* d_ws, size_t ws_size,
                              hipStream_t stream) {
    const float* latents = (const float*)d_in[0];
    const float* cb      = (const float*)d_in[1];
    float*       e2      = (float*)d_ws;      // 1024 floats scratch
    float*       out     = (float*)d_out;

    vq_e2_kernel<<<dim3(VQ_K / 128), dim3(128), 0, stream>>>(cb, e2);
    vq_main_kernel<<<dim3(VQ_NPIX / 64), dim3(256), 0, stream>>>(
        latents, (const float4*)cb, e2, out);
}

// Round 3
// 315.103 us; speedup vs baseline: 3.7898x; 3.7898x over previous
//
#include <hip/hip_runtime.h>

// VectorQuantizer: latents (16,128,64,64) f32, codebook (1024,128) f32.
// out[b,d,h,w] = codebook[argmin_k ((x2 - 2*dot(x,e_k)) + e2_k)][d]
// Numerics: serial ascending-d fp32 fma chain for dot and x2;
// t3 = (x2 - 2*dot) + e2 (two roundings); argmin first-index-wins
// (lexicographic (value,index) merge).
//
// GEMM-style: block = 256 thr / 4 waves, tile 64 px x 1024 codes.
// LDS d-major tiles read with ds_read_b128 along the minor dim (px / code):
// all compute-phase LDS accesses are broadcast or 2-way (free). Codebook
// streamed via VECTOR loads only (round-2 lesson: the SMEM path thrashed
// HBM, 3.45 GB fetched). Thread tile 8px x 8codes = 64 acc VGPRs; 4 b128
// per 64 FMA -> ~1 B/FMA, LDS-roofline ~165 us, VALU ~109 us.

#define VQ_D 128
#define VQ_K 1024
#define VQ_HW 4096

__global__ __launch_bounds__(128, 2)
void vq_e2_kernel(const float* __restrict__ cb, float* __restrict__ e2) {
    int k = blockIdx.x * blockDim.x + threadIdx.x;
    if (k < VQ_K) {
        float s = 0.f;
        #pragma unroll
        for (int d = 0; d < VQ_D; ++d) {
            float v = cb[k * VQ_D + d];
            s = fmaf(v, v, s);
        }
        e2[k] = s;
    }
}

// smem layout (bytes):
//   xl   @ 0      : float[128][64]  x-tile, d-major              (32768)
//   cbl  @ 32768  : float[16][256]  cb chunk, d-major            (16384)
//        (overlaid after compute by mval[32][64] + midx[32][64])
//   x2s  @ 49152  : float[64]
//   fbis @ 49408  : int[64]
__global__ __launch_bounds__(256, 3)
void vq_main_kernel(const float* __restrict__ latents,
                    const float* __restrict__ cb,
                    const float* __restrict__ e2,
                    float* __restrict__ out) {
    __shared__ __align__(16) char smem[49664];
    float* xl   = (float*)smem;                    // [128][64]
    float* cbl  = (float*)(smem + 32768);          // [16][256]
    float* mval = (float*)(smem + 32768);          // [32][64] overlay
    int*   midx = (int*)(smem + 32768 + 8192);     // [32][64] overlay
    float* x2s  = (float*)(smem + 49152);          // [64]
    int*   fbis = (int*)(smem + 49408);            // [64]

    const int tid  = threadIdx.x;
    const int w    = tid >> 6;        // wave 0..3
    const int lane = tid & 63;
    const int tp   = lane & 7;        // px-group:   px = tp*8 + pp
    const int tc   = lane >> 3;       // code-group: k  = kt*256 + w*64 + tc*8 + j
    const int blk  = blockIdx.x;
    const int b    = blk >> 6;        // 64 blocks per image
    const int hw0  = (blk & 63) << 6;

    const float* xg = latents + ((size_t)b * VQ_D) * VQ_HW + hw0;

    // ---- stage x-tile: [d][px], coalesced f4 along px ----
    {
        const int px4 = (tid & 15) << 2;
        const int db  = (tid >> 4) << 3;
        #pragma unroll
        for (int i = 0; i < 8; ++i) {
            const int d = db + i;
            const float4 v = *(const float4*)(xg + (size_t)d * VQ_HW + px4);
            *(float4*)(xl + d * 64 + px4) = v;
        }
    }
    __syncthreads();

    // ---- x2 per pixel: serial ascending-d chain (one thread per px) ----
    if (tid < 64) {
        float s = 0.f;
        #pragma unroll
        for (int d = 0; d < VQ_D; ++d) {
            const float v = xl[d * 64 + tid];
            s = fmaf(v, v, s);
        }
        x2s[tid] = s;   // ordered for readers by the syncs inside the kt loop
    }

    float bestv[8];
    int   besti[8];
    #pragma unroll
    for (int pp = 0; pp < 8; ++pp) { bestv[pp] = 1e30f; besti[pp] = 0; }

    #pragma unroll 1
    for (int kt = 0; kt < 4; ++kt) {
        float acc[8][8];
        #pragma unroll
        for (int pp = 0; pp < 8; ++pp)
            #pragma unroll
            for (int j = 0; j < 8; ++j) acc[pp][j] = 0.f;

        #pragma unroll 1
        for (int ds = 0; ds < 8; ++ds) {
            __syncthreads();   // previous chunk's readers done before overwrite
            // stage cb chunk: one code row per thread, 16 d's, vector loads
            {
                const float* crow =
                    cb + (size_t)(kt * 256 + tid) * VQ_D + ds * 16;
                const float4 q0 = *(const float4*)(crow + 0);
                const float4 q1 = *(const float4*)(crow + 4);
                const float4 q2 = *(const float4*)(crow + 8);
                const float4 q3 = *(const float4*)(crow + 12);
                cbl[ 0 * 256 + tid] = q0.x;  cbl[ 1 * 256 + tid] = q0.y;
                cbl[ 2 * 256 + tid] = q0.z;  cbl[ 3 * 256 + tid] = q0.w;
                cbl[ 4 * 256 + tid] = q1.x;  cbl[ 5 * 256 + tid] = q1.y;
                cbl[ 6 * 256 + tid] = q1.z;  cbl[ 7 * 256 + tid] = q1.w;
                cbl[ 8 * 256 + tid] = q2.x;  cbl[ 9 * 256 + tid] = q2.y;
                cbl[10 * 256 + tid] = q2.z;  cbl[11 * 256 + tid] = q2.w;
                cbl[12 * 256 + tid] = q3.x;  cbl[13 * 256 + tid] = q3.y;
                cbl[14 * 256 + tid] = q3.z;  cbl[15 * 256 + tid] = q3.w;
            }
            __syncthreads();

            // compute: 16 d's, 4 ds_read_b128 + 64 FMA per d
            #pragma unroll 4
            for (int dq = 0; dq < 16; ++dq) {
                const int d = ds * 16 + dq;
                const float4 xa = *(const float4*)(xl + d * 64 + tp * 8);
                const float4 xb = *(const float4*)(xl + d * 64 + tp * 8 + 4);
                const float4 c0 = *(const float4*)(cbl + dq * 256 + w * 64 + tc * 8);
                const float4 c1 = *(const float4*)(cbl + dq * 256 + w * 64 + tc * 8 + 4);
                const float xs[8] = {xa.x, xa.y, xa.z, xa.w, xb.x, xb.y, xb.z, xb.w};
                const float cs[8] = {c0.x, c0.y, c0.z, c0.w, c1.x, c1.y, c1.z, c1.w};
                #pragma unroll
                for (int pp = 0; pp < 8; ++pp)
                    #pragma unroll
                    for (int j = 0; j < 8; ++j)
                        acc[pp][j] = fmaf(xs[pp], cs[j], acc[pp][j]);
            }
        }

        // epilogue for this 256-code tile
        const int k0 = kt * 256 + w * 64 + tc * 8;
        const float4 e0 = *(const float4*)(e2 + k0);
        const float4 e1 = *(const float4*)(e2 + k0 + 4);
        const float ev[8] = {e0.x, e0.y, e0.z, e0.w, e1.x, e1.y, e1.z, e1.w};
        #pragma unroll
        for (int pp = 0; pp < 8; ++pp) {
            const float x2 = x2s[tp * 8 + pp];
            #pragma unroll
            for (int j = 0; j < 8; ++j) {
                const float t3 = (x2 - 2.0f * acc[pp][j]) + ev[j];
                if (t3 < bestv[pp]) { bestv[pp] = t3; besti[pp] = k0 + j; }
            }
        }
    }

    // ---- merge: overlay cbl with (val, idx); lexicographic (v, i) ----
    __syncthreads();   // all compute-phase cbl readers done
    #pragma unroll
    for (int pp = 0; pp < 8; ++pp) {
        mval[(w * 8 + tc) * 64 + tp * 8 + pp] = bestv[pp];
        midx[(w * 8 + tc) * 64 + tp * 8 + pp] = besti[pp];
    }
    __syncthreads();
    if (tid < 64) {
        float bv = mval[tid];
        int   bi = midx[tid];
        #pragma unroll
        for (int e = 1; e < 32; ++e) {
            const float v = mval[e * 64 + tid];
            const int   i = midx[e * 64 + tid];
            if (v < bv || (v == bv && i < bi)) { bv = v; bi = i; }
        }
        fbis[tid] = bi;
    }
    __syncthreads();

    // ---- writeback: thread t -> px = t&63, d-range (t>>6)*32 .. +32 ----
    {
        const int px = tid & 63;
        const int dh = tid >> 6;
        const int fb = fbis[px];
        const float* crow = cb + (size_t)fb * VQ_D;
        float* og = out + ((size_t)b * VQ_D) * VQ_HW + hw0;
        #pragma unroll
        for (int i = 0; i < 32; ++i) {
            const int d = dh * 32 + i;
            og[(size_t)d * VQ_HW + px] = crow[d];
        }
    }
}

extern "C" void kernel_launch(void* const* d_in, const int* in_sizes, int n_in,
                              void* d_out, int out_size, void* d_ws, size_t ws_size,
                              hipStream_t stream) {
    const float* latents = (const float*)d_in[0];
    const float* cb      = (const float*)d_in[1];
    float*       e2      = (float*)d_ws;      // 1024 floats scratch
    float*       out     = (float*)d_out;

    vq_e2_kernel<<<dim3(VQ_K / 128), dim3(128), 0, stream>>>(cb, e2);
    vq_main_kernel<<<dim3(1024), dim3(256), 0, stream>>>(latents, cb, e2, out);
}

// Round 4
// 192.598 us; speedup vs baseline: 6.2003x; 1.6361x over previous
//
#include <hip/hip_runtime.h>

// VectorQuantizer: latents (16,128,64,64) f32, codebook (1024,128) f32.
// out[b,d,h,w] = codebook[argmin_k fl(fl(x2 - 2*dot(x,e_k)) + e2_k)][d]
//
// MFMA bf16 scoring + exact fp32 rescue:
//  phase 1: 16x16x32 bf16 MFMA scores (fp32 acc) -> per-px bf16 min.
//  phase 2: recompute scores; candidates = { k : S_bf <= min + 2*M[px] },
//           M from Cauchy-Schwarz: |S_bf-S_fp| <= 2*2^-7*sqrt(x2*e2max)+slop,
//           e2max <= 128*(1/1024)^2 (input spec) -> M = 2e-4*sqrt(x2)+1.5e-4.
//  rescue:  exact fp32 serial ascending-d fmaf chain (round-1-validated
//           numerics) on ~1.8 candidates/px; lex (t3,k) u64 atomicMin keeps
//           np first-index tie-break (t3 > 0 always -> float bits monotonic).
// Codebook streamed as bf16 [k][d] from L2 (256 KB resident); round-2 lesson:
// never route cb through SMEM. A-frags live in 64 VGPRs for the whole sweep.

typedef __attribute__((ext_vector_type(8))) short short8;
typedef __attribute__((ext_vector_type(4))) float f32x4;

#define VQ_D 128
#define VQ_K 1024
#define VQ_HW 4096

__device__ inline unsigned short f2bf(float f) {   // RNE fp32->bf16
    unsigned u = __float_as_uint(f);
    return (unsigned short)((u + 0x7FFFu + ((u >> 16) & 1u)) >> 16);
}

__global__ __launch_bounds__(128)
void vq_prep_kernel(const float* __restrict__ cb, unsigned short* __restrict__ cbbf,
                    float* __restrict__ e2) {
    const int k = blockIdx.x * 128 + threadIdx.x;
    const float* crow = cb + (size_t)k * VQ_D;
    unsigned short* brow = cbbf + (size_t)k * VQ_D;
    float s = 0.f;
    #pragma unroll
    for (int d = 0; d < VQ_D; ++d) {
        const float v = crow[d];
        s = fmaf(v, v, s);          // serial chain (same as rounds 1-3)
        brow[d] = f2bf(v);
    }
    e2[k] = s;
}

__global__ __launch_bounds__(256, 3)
void vq_main_kernel(const float* __restrict__ latents,
                    const float* __restrict__ cb,
                    const unsigned short* __restrict__ cbbf,
                    const float* __restrict__ e2,
                    float* __restrict__ out) {
    __shared__ __align__(16) float xl[VQ_D * 64];   // [d][px] 32 KB
    __shared__ float x2s[64];
    __shared__ float bfminw[4][64];
    __shared__ float threshs[64];
    __shared__ unsigned long long fkey[64];
    __shared__ unsigned int cand[2048];
    __shared__ int ncand;

    const int tid  = threadIdx.x;
    const int lane = tid & 63;
    const int wave = __builtin_amdgcn_readfirstlane(tid >> 6);
    const int quad = lane >> 4;
    const int mm   = lane & 15;
    const int blk  = blockIdx.x;
    const int b    = blk >> 6;
    const int hw0  = (blk & 63) << 6;

    const float* xg = latents + (size_t)b * VQ_D * VQ_HW + hw0;

    // ---- stage x tile [d][px], coalesced float4 ----
    {
        const int px4 = (tid & 15) << 2;
        const int db  = (tid >> 4) << 3;
        #pragma unroll
        for (int i = 0; i < 8; ++i) {
            const int d = db + i;
            *(float4*)(xl + d * 64 + px4) =
                *(const float4*)(xg + (size_t)d * VQ_HW + px4);
        }
    }
    if (tid == 0) ncand = 0;
    if (tid < 64) fkey[tid] = ~0ULL;
    __syncthreads();

    // x2 per px: serial ascending-d chain
    if (tid < 64) {
        float s = 0.f;
        #pragma unroll
        for (int d = 0; d < VQ_D; ++d) {
            const float v = xl[d * 64 + tid];
            s = fmaf(v, v, s);
        }
        x2s[tid] = s;
    }

    // ---- A fragments (held in VGPRs all sweep): px=p*16+mm, d=t*32+quad*8+j
    short8 A[16];
    #pragma unroll
    for (int p = 0; p < 4; ++p) {
        #pragma unroll
        for (int t = 0; t < 4; ++t) {
            short8 a;
            #pragma unroll
            for (int j = 0; j < 8; ++j) {
                const float v = xl[(t * 32 + quad * 8 + j) * 64 + p * 16 + mm];
                a[j] = (short)f2bf(v);
            }
            A[p * 4 + t] = a;
        }
    }

    float e2r[16];
    #pragma unroll
    for (int c = 0; c < 16; ++c) e2r[c] = e2[wave * 256 + c * 16 + mm];

    __syncthreads();   // x2s ready

    float x2r[16];
    #pragma unroll
    for (int p = 0; p < 4; ++p)
        #pragma unroll
        for (int r = 0; r < 4; ++r)
            x2r[p * 4 + r] = x2s[p * 16 + quad * 4 + r];

    // B-frag base: code = wave*256 + c*16 + mm, d = t*32 + quad*8 + j
    const unsigned short* bbase = cbbf + (size_t)(wave * 256 + mm) * VQ_D + quad * 8;

    // ---- phase 1: bf16 score min per px ----
    float bmin[16];
    #pragma unroll
    for (int i = 0; i < 16; ++i) bmin[i] = 1e30f;

    #pragma unroll 1
    for (int c = 0; c < 16; ++c) {
        short8 B[4];
        #pragma unroll
        for (int t = 0; t < 4; ++t)
            B[t] = *(const short8*)(bbase + (size_t)c * 16 * VQ_D + t * 32);
        f32x4 C[4] = {{0.f,0.f,0.f,0.f},{0.f,0.f,0.f,0.f},
                      {0.f,0.f,0.f,0.f},{0.f,0.f,0.f,0.f}};
        #pragma unroll
        for (int t = 0; t < 4; ++t)
            #pragma unroll
            for (int p = 0; p < 4; ++p)
                C[p] = __builtin_amdgcn_mfma_f32_16x16x32_bf16(
                           A[p * 4 + t], B[t], C[p], 0, 0, 0);
        #pragma unroll
        for (int p = 0; p < 4; ++p)
            #pragma unroll
            for (int r = 0; r < 4; ++r) {
                const float s = (x2r[p * 4 + r] - 2.0f * C[p][r]) + e2r[c];
                bmin[p * 4 + r] = fminf(bmin[p * 4 + r], s);
            }
    }

    // reduce min across the 16 lanes of each quad-group (code dimension)
    #pragma unroll
    for (int i = 0; i < 16; ++i) {
        float v = bmin[i];
        v = fminf(v, __shfl_xor(v, 1));
        v = fminf(v, __shfl_xor(v, 2));
        v = fminf(v, __shfl_xor(v, 4));
        v = fminf(v, __shfl_xor(v, 8));
        bmin[i] = v;
    }
    if (mm == 0) {
        #pragma unroll
        for (int p = 0; p < 4; ++p)
            #pragma unroll
            for (int r = 0; r < 4; ++r)
                bfminw[wave][p * 16 + quad * 4 + r] = bmin[p * 4 + r];
    }
    __syncthreads();
    if (tid < 64) {
        const float mn = fminf(fminf(bfminw[0][tid], bfminw[1][tid]),
                               fminf(bfminw[2][tid], bfminw[3][tid]));
        const float M = 2.0e-4f * sqrtf(x2s[tid]) + 1.5e-4f;
        threshs[tid] = mn + 2.0f * M;
    }
    __syncthreads();

    float thr[16];
    #pragma unroll
    for (int p = 0; p < 4; ++p)
        #pragma unroll
        for (int r = 0; r < 4; ++r)
            thr[p * 4 + r] = threshs[p * 16 + quad * 4 + r];

    // ---- phase 2: recompute, collect candidates ----
    #pragma unroll 1
    for (int c = 0; c < 16; ++c) {
        short8 B[4];
        #pragma unroll
        for (int t = 0; t < 4; ++t)
            B[t] = *(const short8*)(bbase + (size_t)c * 16 * VQ_D + t * 32);
        f32x4 C[4] = {{0.f,0.f,0.f,0.f},{0.f,0.f,0.f,0.f},
                      {0.f,0.f,0.f,0.f},{0.f,0.f,0.f,0.f}};
        #pragma unroll
        for (int t = 0; t < 4; ++t)
            #pragma unroll
            for (int p = 0; p < 4; ++p)
                C[p] = __builtin_amdgcn_mfma_f32_16x16x32_bf16(
                           A[p * 4 + t], B[t], C[p], 0, 0, 0);
        #pragma unroll
        for (int p = 0; p < 4; ++p)
            #pragma unroll
            for (int r = 0; r < 4; ++r) {
                const float s = (x2r[p * 4 + r] - 2.0f * C[p][r]) + e2r[c];
                if (s <= thr[p * 4 + r]) {
                    const int idx = atomicAdd(&ncand, 1);
                    if (idx < 2048) {
                        const int px   = p * 16 + quad * 4 + r;
                        const int code = wave * 256 + c * 16 + mm;
                        cand[idx] = ((unsigned)px << 16) | (unsigned)code;
                    }
                }
            }
    }
    __syncthreads();

    // ---- rescue: exact fp32 serial chain on candidates, one per lane ----
    const int nc = ncand < 2048 ? ncand : 2048;
    for (int i = tid; i < nc; i += 256) {
        const unsigned pc = cand[i];
        const int px = (int)(pc >> 16);
        const int k  = (int)(pc & 0xFFFFu);
        const float* crow = cb + (size_t)k * VQ_D;
        float dot = 0.f;
        #pragma unroll
        for (int q = 0; q < 32; ++q) {
            const float4 cv = *(const float4*)(crow + q * 4);
            dot = fmaf(xl[(q * 4 + 0) * 64 + px], cv.x, dot);
            dot = fmaf(xl[(q * 4 + 1) * 64 + px], cv.y, dot);
            dot = fmaf(xl[(q * 4 + 2) * 64 + px], cv.z, dot);
            dot = fmaf(xl[(q * 4 + 3) * 64 + px], cv.w, dot);
        }
        const float t3 = (x2s[px] - 2.0f * dot) + e2[k];
        const unsigned long long key =
            ((unsigned long long)__float_as_uint(t3) << 32) | (unsigned)k;
        atomicMin(&fkey[px], key);
    }
    __syncthreads();

    // ---- writeback ----
    {
        const int px = tid & 63;
        const int dh = tid >> 6;
        const int fb = (int)(fkey[px] & 0xFFFFFFFFULL);
        const float* crow = cb + (size_t)fb * VQ_D;
        float* og = out + (size_t)b * VQ_D * VQ_HW + hw0;
        #pragma unroll
        for (int i = 0; i < 32; ++i) {
            const int d = dh * 32 + i;
            og[(size_t)d * VQ_HW + px] = crow[d];
        }
    }
}

extern "C" void kernel_launch(void* const* d_in, const int* in_sizes, int n_in,
                              void* d_out, int out_size, void* d_ws, size_t ws_size,
                              hipStream_t stream) {
    const float* latents = (const float*)d_in[0];
    const float* cb      = (const float*)d_in[1];
    unsigned short* cbbf = (unsigned short*)d_ws;              // 256 KB
    float* e2            = (float*)((char*)d_ws + 262144);     // 4 KB
    float* out           = (float*)d_out;

    vq_prep_kernel<<<dim3(8), dim3(128), 0, stream>>>(cb, cbbf, e2);
    vq_main_kernel<<<dim3(1024), dim3(256), 0, stream>>>(latents, cb, cbbf, e2, out);
}